// Round 1
// baseline (459.458 us; speedup 1.0000x reference)
//
#include <hip/hip_runtime.h>
#include <hip/hip_bf16.h>
#include <hip/hip_fp16.h>

typedef __bf16 bf16x8 __attribute__((ext_vector_type(8)));
typedef float  f32x4  __attribute__((ext_vector_type(4)));

// ---------- helpers ----------

__device__ inline float blk_absmax(float v, float* red) {
#pragma unroll
  for (int off = 32; off; off >>= 1) v = fmaxf(v, __shfl_xor(v, off));
  __syncthreads();                       // protect red[] reuse across calls
  if ((threadIdx.x & 63) == 0) red[threadIdx.x >> 6] = v;
  __syncthreads();
  return fmaxf(fmaxf(red[0], red[1]), fmaxf(red[2], red[3]));
}

__device__ inline float f16round(float s) {   // s.astype(f16).astype(f32)
  return __half2float(__float2half(s));
}

__device__ inline unsigned short q2bf(float v) {  // exact for |v|<=127 integers
  __hip_bfloat16 b = __float2bfloat16(v);
  return __builtin_bit_cast(unsigned short, b);
}

__device__ inline float qclip(float x, float s, float qmax) {
  return fminf(fmaxf(rintf(x / s), -qmax), qmax);   // rintf = round-half-even (matches jnp.round)
}

// ---------- activation quant: x (M x 4096 f32) -> xq bf16 + xs f32 ----------

__global__ __launch_bounds__(256) void quant_x_kernel(
    const float* __restrict__ x, unsigned short* __restrict__ xq,
    float* __restrict__ xs, int C) {
  __shared__ float red[4];
  int row = blockIdx.x, t = threadIdx.x;
  const float4* src = (const float4*)(x + (size_t)row * C);
  float4 v[4];
  float m = 0.f;
#pragma unroll
  for (int i = 0; i < 4; ++i) {
    v[i] = src[t + i * 256];
    m = fmaxf(m, fmaxf(fmaxf(fabsf(v[i].x), fabsf(v[i].y)),
                       fmaxf(fabsf(v[i].z), fabsf(v[i].w))));
  }
  m = blk_absmax(m, red);
  float s = fmaxf(m, 1e-8f) / 127.0f;     // x_scale stays fp32 (no f16 round)
  if (t == 0) xs[row] = s;
  ushort4* dst = (ushort4*)(xq + (size_t)row * C);
#pragma unroll
  for (int i = 0; i < 4; ++i) {
    ushort4 o;
    o.x = q2bf(qclip(v[i].x, s, 127.f));
    o.y = q2bf(qclip(v[i].y, s, 127.f));
    o.z = q2bf(qclip(v[i].z, s, 127.f));
    o.w = q2bf(qclip(v[i].w, s, 127.f));
    dst[t + i * 256] = o;
  }
}

// ---------- weight quant: v rows (gathered), high qmax=127, low qmax=7 ----------

__global__ __launch_bounds__(256) void quant_v_kernel(
    const float* __restrict__ vw, const int* __restrict__ hi,
    const int* __restrict__ lo, int r_high,
    unsigned short* __restrict__ vq, float* __restrict__ vs, int C) {
  __shared__ float red[4];
  int b = blockIdx.x, t = threadIdx.x;
  int srow; float qmax;
  if (b < r_high) { srow = hi[b]; qmax = 127.f; }
  else            { srow = lo[b - r_high]; qmax = 7.f; }
  const float4* src = (const float4*)(vw + (size_t)srow * C);
  float4 v[4];
  float m = 0.f;
#pragma unroll
  for (int i = 0; i < 4; ++i) {
    v[i] = src[t + i * 256];
    m = fmaxf(m, fmaxf(fmaxf(fabsf(v[i].x), fabsf(v[i].y)),
                       fmaxf(fabsf(v[i].z), fabsf(v[i].w))));
  }
  m = blk_absmax(m, red);
  float s = fmaxf(m, 1e-8f) / qmax;       // quantize with fp32 scale
  if (t == 0) vs[b] = f16round(s);        // but output-scale goes through f16
  ushort4* dst = (ushort4*)(vq + (size_t)b * C);
#pragma unroll
  for (int i = 0; i < 4; ++i) {
    ushort4 o;
    o.x = q2bf(qclip(v[i].x, s, qmax));
    o.y = q2bf(qclip(v[i].y, s, qmax));
    o.z = q2bf(qclip(v[i].z, s, qmax));
    o.w = q2bf(qclip(v[i].w, s, qmax));
    dst[t + i * 256] = o;
  }
}

// ---------- weight quant: u rows = u_weight[i, idx] gathered columns ----------
// uq combined layout: row i = [high cols 0..255 | low cols 256..1023]

__global__ __launch_bounds__(256) void quant_u_kernel(
    const float* __restrict__ uw, const int* __restrict__ hi,
    const int* __restrict__ lo, int r_high, int rank,
    unsigned short* __restrict__ uq, float* __restrict__ ush,
    float* __restrict__ usl) {
  __shared__ float red[4];
  int i = blockIdx.x, t = threadIdx.x;
  const float* urow = uw + (size_t)i * rank;
  // high path (r_high == 256 == blockDim)
  float hv = urow[hi[t]];
  float mh = blk_absmax(fabsf(hv), red);
  float sh = fmaxf(mh, 1e-8f) / 127.f;
  uq[(size_t)i * rank + t] = q2bf(qclip(hv, sh, 127.f));
  if (t == 0) ush[i] = f16round(sh);
  // low path (768 = 3*256)
  float lv[3]; float ml = 0.f;
#pragma unroll
  for (int j = 0; j < 3; ++j) {
    lv[j] = urow[lo[t + j * 256]];
    ml = fmaxf(ml, fabsf(lv[j]));
  }
  ml = blk_absmax(ml, red);
  float sl = fmaxf(ml, 1e-8f) / 7.f;
#pragma unroll
  for (int j = 0; j < 3; ++j)
    uq[(size_t)i * rank + r_high + t + j * 256] = q2bf(qclip(lv[j], sl, 7.f));
  if (t == 0) usl[i] = f16round(sl);
}

// ---------- re-quant of y1: split-row absmax (high cols [0,256), low [256,1024)) ----------

__global__ __launch_bounds__(256) void quant_y1_kernel(
    const float* __restrict__ y1, unsigned short* __restrict__ y1q,
    float* __restrict__ s2h, float* __restrict__ s2l, int N, int r_high) {
  __shared__ float red[4];
  int row = blockIdx.x, t = threadIdx.x;
  float4 v = ((const float4*)(y1 + (size_t)row * N))[t];
  float a = fmaxf(fmaxf(fabsf(v.x), fabsf(v.y)), fmaxf(fabsf(v.z), fabsf(v.w)));
  bool ishigh = (t * 4) < r_high;
  float mh = blk_absmax(ishigh ? a : 0.f, red);
  float ml = blk_absmax(ishigh ? 0.f : a, red);
  float sh = fmaxf(mh, 1e-8f) / 127.f;
  float sl = fmaxf(ml, 1e-8f) / 127.f;
  float s = ishigh ? sh : sl;
  ushort4 o;
  o.x = q2bf(qclip(v.x, s, 127.f));
  o.y = q2bf(qclip(v.y, s, 127.f));
  o.z = q2bf(qclip(v.z, s, 127.f));
  o.w = q2bf(qclip(v.w, s, 127.f));
  ((ushort4*)(y1q + (size_t)row * N))[t] = o;
  if (t == 0) { s2h[row] = sh; s2l[row] = sl; }
}

// ---------- GEMM common geometry ----------
// 128x128 tile, BK=64, 256 threads = 4 waves in 2x2; each wave 64x64 = 4x4 frags
// of mfma_f32_16x16x32_bf16. LDS layout: [row][64] bf16 with XOR swizzle on 16B
// groups: byte = row*128 + ((g ^ (row&7))<<4), g = k/8  -> <=2-way bank conflict.

#define BM 128
#define BN 128
#define BKT 64

__global__ __launch_bounds__(256) void gemm1_kernel(
    const unsigned short* __restrict__ A,   // xq: M x K bf16 bits
    const unsigned short* __restrict__ B,   // vq: N x K bf16 bits
    const float* __restrict__ xs, const float* __restrict__ ws,
    float* __restrict__ Y, int M, int N, int K) {
  __shared__ char smA[BM * BKT * 2];
  __shared__ char smB[BN * BKT * 2];
  int m0 = blockIdx.y * BM, n0 = blockIdx.x * BN;
  int tid = threadIdx.x, l = tid & 63, w = tid >> 6;
  int wr = w >> 1, wc = w & 1;
  f32x4 acc[4][4] = {};
  for (int k0 = 0; k0 < K; k0 += BKT) {
    __syncthreads();
#pragma unroll
    for (int c = tid; c < (BM * BKT) / 8; c += 256) {
      int row = c >> 3, g = c & 7;
      int sw = ((g ^ (row & 7)) << 4);
      *(uint4*)(smA + row * 128 + sw) =
          *(const uint4*)(A + (size_t)(m0 + row) * K + k0 + g * 8);
      *(uint4*)(smB + row * 128 + sw) =
          *(const uint4*)(B + (size_t)(n0 + row) * K + k0 + g * 8);
    }
    __syncthreads();
#pragma unroll
    for (int kk = 0; kk < BKT / 32; ++kk) {
      bf16x8 af[4], bb[4];
      int lk = kk * 4 + (l >> 4);
#pragma unroll
      for (int f = 0; f < 4; ++f) {
        int ar = wr * 64 + f * 16 + (l & 15);
        af[f] = *(const bf16x8*)(smA + ar * 128 + ((lk ^ (ar & 7)) << 4));
        int br = wc * 64 + f * 16 + (l & 15);
        bb[f] = *(const bf16x8*)(smB + br * 128 + ((lk ^ (br & 7)) << 4));
      }
#pragma unroll
      for (int i2 = 0; i2 < 4; ++i2)
#pragma unroll
        for (int j2 = 0; j2 < 4; ++j2)
          acc[i2][j2] = __builtin_amdgcn_mfma_f32_16x16x32_bf16(
              af[i2], bb[j2], acc[i2][j2], 0, 0, 0);
    }
  }
#pragma unroll
  for (int i2 = 0; i2 < 4; ++i2)
#pragma unroll
    for (int j2 = 0; j2 < 4; ++j2) {
      int col = n0 + wc * 64 + j2 * 16 + (l & 15);
      float cs = ws[col];
#pragma unroll
      for (int r = 0; r < 4; ++r) {
        int row = m0 + wr * 64 + i2 * 16 + (l >> 4) * 4 + r;
        Y[(size_t)row * N + col] = acc[i2][j2][r] * xs[row] * cs;
      }
    }
}

__global__ __launch_bounds__(256) void gemm2_kernel(
    const unsigned short* __restrict__ A,   // y1q: M x K
    const unsigned short* __restrict__ B,   // uq:  N x K
    const float* __restrict__ s2h, const float* __restrict__ s2l,
    const float* __restrict__ ush, const float* __restrict__ usl,
    const float* __restrict__ bias,
    float* __restrict__ Out, int M, int N, int K, int r_high) {
  __shared__ char smA[BM * BKT * 2];
  __shared__ char smB[BN * BKT * 2];
  int m0 = blockIdx.y * BM, n0 = blockIdx.x * BN;
  int tid = threadIdx.x, l = tid & 63, w = tid >> 6;
  int wr = w >> 1, wc = w & 1;
  f32x4 acch[4][4] = {};
  f32x4 accl[4][4] = {};

  auto ktile = [&](int k0, f32x4(&acc)[4][4]) {
    __syncthreads();
#pragma unroll
    for (int c = tid; c < (BM * BKT) / 8; c += 256) {
      int row = c >> 3, g = c & 7;
      int sw = ((g ^ (row & 7)) << 4);
      *(uint4*)(smA + row * 128 + sw) =
          *(const uint4*)(A + (size_t)(m0 + row) * K + k0 + g * 8);
      *(uint4*)(smB + row * 128 + sw) =
          *(const uint4*)(B + (size_t)(n0 + row) * K + k0 + g * 8);
    }
    __syncthreads();
#pragma unroll
    for (int kk = 0; kk < BKT / 32; ++kk) {
      bf16x8 af[4], bb[4];
      int lk = kk * 4 + (l >> 4);
#pragma unroll
      for (int f = 0; f < 4; ++f) {
        int ar = wr * 64 + f * 16 + (l & 15);
        af[f] = *(const bf16x8*)(smA + ar * 128 + ((lk ^ (ar & 7)) << 4));
        int br = wc * 64 + f * 16 + (l & 15);
        bb[f] = *(const bf16x8*)(smB + br * 128 + ((lk ^ (br & 7)) << 4));
      }
#pragma unroll
      for (int i2 = 0; i2 < 4; ++i2)
#pragma unroll
        for (int j2 = 0; j2 < 4; ++j2)
          acc[i2][j2] = __builtin_amdgcn_mfma_f32_16x16x32_bf16(
              af[i2], bb[j2], acc[i2][j2], 0, 0, 0);
    }
  };

  for (int k0 = 0; k0 < r_high; k0 += BKT) ktile(k0, acch);   // high: k in [0,256)
  for (int k0 = r_high; k0 < K; k0 += BKT) ktile(k0, accl);   // low:  k in [256,1024)

#pragma unroll
  for (int i2 = 0; i2 < 4; ++i2)
#pragma unroll
    for (int j2 = 0; j2 < 4; ++j2) {
      int col = n0 + wc * 64 + j2 * 16 + (l & 15);
      float uh = ush[col], ul = usl[col];
      float bc = f16round(bias[col]);
#pragma unroll
      for (int r = 0; r < 4; ++r) {
        int row = m0 + wr * 64 + i2 * 16 + (l >> 4) * 4 + r;
        Out[(size_t)row * N + col] =
            acch[i2][j2][r] * (s2h[row] * uh) +
            accl[i2][j2][r] * (s2l[row] * ul) + bc;
      }
    }
}

// ---------- launch ----------

extern "C" void kernel_launch(void* const* d_in, const int* in_sizes, int n_in,
                              void* d_out, int out_size, void* d_ws, size_t ws_size,
                              hipStream_t stream) {
  const float* x    = (const float*)d_in[0];
  const float* uw   = (const float*)d_in[1];
  const float* vw   = (const float*)d_in[2];
  const float* bias = (const float*)d_in[3];
  const int*   hi   = (const int*)d_in[4];
  const int*   lo   = (const int*)d_in[5];

  const int in_f = 4096, out_f = 4096;
  const int rank   = in_sizes[1] / out_f;     // 1024
  const int r_high = in_sizes[4];             // 256
  const int M      = in_sizes[0] / in_f;      // 8192

  char* p = (char*)d_ws;
  auto take = [&](size_t bytes) {
    char* r = p;
    p += (bytes + 255) & ~(size_t)255;
    return r;
  };
  unsigned short* xq  = (unsigned short*)take((size_t)M * in_f * 2);
  float*          xs  = (float*)take((size_t)M * 4);
  unsigned short* vq  = (unsigned short*)take((size_t)rank * in_f * 2);
  float*          vs  = (float*)take((size_t)rank * 4);
  unsigned short* uq  = (unsigned short*)take((size_t)out_f * rank * 2);
  float*          ush = (float*)take((size_t)out_f * 4);
  float*          usl = (float*)take((size_t)out_f * 4);
  float*          y1  = (float*)take((size_t)M * rank * 4);
  unsigned short* y1q = (unsigned short*)take((size_t)M * rank * 2);
  float*          s2h = (float*)take((size_t)M * 4);
  float*          s2l = (float*)take((size_t)M * 4);

  quant_x_kernel<<<M, 256, 0, stream>>>(x, xq, xs, in_f);
  quant_v_kernel<<<rank, 256, 0, stream>>>(vw, hi, lo, r_high, vq, vs, in_f);
  quant_u_kernel<<<out_f, 256, 0, stream>>>(uw, hi, lo, r_high, rank, uq, ush, usl);
  gemm1_kernel<<<dim3(rank / BN, M / BM), 256, 0, stream>>>(xq, vq, xs, vs, y1,
                                                            M, rank, in_f);
  quant_y1_kernel<<<M, 256, 0, stream>>>(y1, y1q, s2h, s2l, rank, r_high);
  gemm2_kernel<<<dim3(out_f / BN, M / BM), 256, 0, stream>>>(
      y1q, uq, s2h, s2l, ush, usl, bias, (float*)d_out, M, out_f, rank, r_high);
}

// Round 2
// 315.358 us; speedup vs baseline: 1.4569x; 1.4569x over previous
//
#include <hip/hip_runtime.h>
#include <hip/hip_bf16.h>
#include <hip/hip_fp16.h>

typedef __bf16 bf16x8 __attribute__((ext_vector_type(8)));
typedef float  f32x4  __attribute__((ext_vector_type(4)));

// global -> LDS direct DMA, 16B per lane, linear LDS dest (base + lane*16)
#define GLD16(gp, lp)                                                   \
  __builtin_amdgcn_global_load_lds(                                     \
      (const __attribute__((address_space(1))) unsigned int*)(gp),      \
      (__attribute__((address_space(3))) unsigned int*)(lp), 16, 0, 0)

// ---------- helpers ----------

__device__ inline float blk_absmax(float v, float* red) {
#pragma unroll
  for (int off = 32; off; off >>= 1) v = fmaxf(v, __shfl_xor(v, off));
  __syncthreads();                       // protect red[] reuse across calls
  if ((threadIdx.x & 63) == 0) red[threadIdx.x >> 6] = v;
  __syncthreads();
  return fmaxf(fmaxf(red[0], red[1]), fmaxf(red[2], red[3]));
}

__device__ inline float f16round(float s) {   // s.astype(f16).astype(f32)
  return __half2float(__float2half(s));
}

__device__ inline unsigned short q2bf(float v) {  // exact for |v|<=127 integers
  __hip_bfloat16 b = __float2bfloat16(v);
  return __builtin_bit_cast(unsigned short, b);
}

__device__ inline float qclip(float x, float s, float qmax) {
  return fminf(fmaxf(rintf(x / s), -qmax), qmax);   // rintf = round-half-even (matches jnp.round)
}

// ---------- activation quant: x (M x 4096 f32) -> xq bf16 + xs f32 ----------

__global__ __launch_bounds__(256) void quant_x_kernel(
    const float* __restrict__ x, unsigned short* __restrict__ xq,
    float* __restrict__ xs, int C) {
  __shared__ float red[4];
  int row = blockIdx.x, t = threadIdx.x;
  const float4* src = (const float4*)(x + (size_t)row * C);
  float4 v[4];
  float m = 0.f;
#pragma unroll
  for (int i = 0; i < 4; ++i) {
    v[i] = src[t + i * 256];
    m = fmaxf(m, fmaxf(fmaxf(fabsf(v[i].x), fabsf(v[i].y)),
                       fmaxf(fabsf(v[i].z), fabsf(v[i].w))));
  }
  m = blk_absmax(m, red);
  float s = fmaxf(m, 1e-8f) / 127.0f;     // x_scale stays fp32 (no f16 round)
  if (t == 0) xs[row] = s;
  ushort4* dst = (ushort4*)(xq + (size_t)row * C);
#pragma unroll
  for (int i = 0; i < 4; ++i) {
    ushort4 o;
    o.x = q2bf(qclip(v[i].x, s, 127.f));
    o.y = q2bf(qclip(v[i].y, s, 127.f));
    o.z = q2bf(qclip(v[i].z, s, 127.f));
    o.w = q2bf(qclip(v[i].w, s, 127.f));
    dst[t + i * 256] = o;
  }
}

// ---------- weight quant: v rows (gathered), high qmax=127, low qmax=7 ----------

__global__ __launch_bounds__(256) void quant_v_kernel(
    const float* __restrict__ vw, const int* __restrict__ hi,
    const int* __restrict__ lo, int r_high,
    unsigned short* __restrict__ vq, float* __restrict__ vs, int C) {
  __shared__ float red[4];
  int b = blockIdx.x, t = threadIdx.x;
  int srow; float qmax;
  if (b < r_high) { srow = hi[b]; qmax = 127.f; }
  else            { srow = lo[b - r_high]; qmax = 7.f; }
  const float4* src = (const float4*)(vw + (size_t)srow * C);
  float4 v[4];
  float m = 0.f;
#pragma unroll
  for (int i = 0; i < 4; ++i) {
    v[i] = src[t + i * 256];
    m = fmaxf(m, fmaxf(fmaxf(fabsf(v[i].x), fabsf(v[i].y)),
                       fmaxf(fabsf(v[i].z), fabsf(v[i].w))));
  }
  m = blk_absmax(m, red);
  float s = fmaxf(m, 1e-8f) / qmax;       // quantize with fp32 scale
  if (t == 0) vs[b] = f16round(s);        // but output-scale goes through f16
  ushort4* dst = (ushort4*)(vq + (size_t)b * C);
#pragma unroll
  for (int i = 0; i < 4; ++i) {
    ushort4 o;
    o.x = q2bf(qclip(v[i].x, s, qmax));
    o.y = q2bf(qclip(v[i].y, s, qmax));
    o.z = q2bf(qclip(v[i].z, s, qmax));
    o.w = q2bf(qclip(v[i].w, s, qmax));
    dst[t + i * 256] = o;
  }
}

// ---------- weight quant: u rows = u_weight[i, idx] gathered columns ----------
// uq combined layout: row i = [high cols 0..255 | low cols 256..1023]

__global__ __launch_bounds__(256) void quant_u_kernel(
    const float* __restrict__ uw, const int* __restrict__ hi,
    const int* __restrict__ lo, int r_high, int rank,
    unsigned short* __restrict__ uq, float* __restrict__ ush,
    float* __restrict__ usl) {
  __shared__ float red[4];
  int i = blockIdx.x, t = threadIdx.x;
  const float* urow = uw + (size_t)i * rank;
  // high path (r_high == 256 == blockDim)
  float hv = urow[hi[t]];
  float mh = blk_absmax(fabsf(hv), red);
  float sh = fmaxf(mh, 1e-8f) / 127.f;
  uq[(size_t)i * rank + t] = q2bf(qclip(hv, sh, 127.f));
  if (t == 0) ush[i] = f16round(sh);
  // low path (768 = 3*256)
  float lv[3]; float ml = 0.f;
#pragma unroll
  for (int j = 0; j < 3; ++j) {
    lv[j] = urow[lo[t + j * 256]];
    ml = fmaxf(ml, fabsf(lv[j]));
  }
  ml = blk_absmax(ml, red);
  float sl = fmaxf(ml, 1e-8f) / 7.f;
#pragma unroll
  for (int j = 0; j < 3; ++j)
    uq[(size_t)i * rank + r_high + t + j * 256] = q2bf(qclip(lv[j], sl, 7.f));
  if (t == 0) usl[i] = f16round(sl);
}

// ---------- re-quant of y1: split-row absmax (high cols [0,256), low [256,1024)) ----------

__global__ __launch_bounds__(256) void quant_y1_kernel(
    const float* __restrict__ y1, unsigned short* __restrict__ y1q,
    float* __restrict__ s2h, float* __restrict__ s2l, int N, int r_high) {
  __shared__ float red[4];
  int row = blockIdx.x, t = threadIdx.x;
  float4 v = ((const float4*)(y1 + (size_t)row * N))[t];
  float a = fmaxf(fmaxf(fabsf(v.x), fabsf(v.y)), fmaxf(fabsf(v.z), fabsf(v.w)));
  bool ishigh = (t * 4) < r_high;
  float mh = blk_absmax(ishigh ? a : 0.f, red);
  float ml = blk_absmax(ishigh ? 0.f : a, red);
  float sh = fmaxf(mh, 1e-8f) / 127.f;
  float sl = fmaxf(ml, 1e-8f) / 127.f;
  float s = ishigh ? sh : sl;
  ushort4 o;
  o.x = q2bf(qclip(v.x, s, 127.f));
  o.y = q2bf(qclip(v.y, s, 127.f));
  o.z = q2bf(qclip(v.z, s, 127.f));
  o.w = q2bf(qclip(v.w, s, 127.f));
  ((ushort4*)(y1q + (size_t)row * N))[t] = o;
  if (t == 0) { s2h[row] = sh; s2l[row] = sl; }
}

// ---------- GEMM common geometry (m97 structure) ----------
// 128x128 tile, BK=64, 256 threads = 4 waves in 2x2; each wave 64x64 = 4x4 frags
// of mfma_f32_16x16x32_bf16.
// Staging: global_load_lds width=16, LINEAR LDS dest (wave base + lane*16).
// The XOR swizzle ((k/8) ^ (row&7)) is applied to the GLOBAL source address so
// the swizzled ds_read_b128 below reads stay bank-conflict-free (rule #21:
// same involution on source-permutation and read-permutation).

#define BM 128
#define BN 128
#define BKT 64

__global__ __launch_bounds__(256) void gemm1_kernel(
    const unsigned short* __restrict__ A,   // xq: M x K bf16 bits
    const unsigned short* __restrict__ B,   // vq: N x K bf16 bits
    const float* __restrict__ xs, const float* __restrict__ ws,
    float* __restrict__ Y, int M, int N, int K) {
  __shared__ char smA[BM * BKT * 2];
  __shared__ char smB[BN * BKT * 2];
  int m0 = blockIdx.y * BM, n0 = blockIdx.x * BN;
  int tid = threadIdx.x, l = tid & 63, w = tid >> 6;
  int wr = w >> 1, wc = w & 1;

  // staging geometry: wave w stages rows [w*32, w*32+32) of each tile,
  // 4 calls x 8 rows; lane l -> row rb+(i*8), 16B slot (l&7).
  int s8 = l & 7;
  int rb = w * 32 + (l >> 3);
  int g  = s8 ^ (rb & 7);                 // pre-swizzled source group
  const unsigned short* pA = A + (size_t)(m0 + rb) * K + g * 8;
  const unsigned short* pB = B + (size_t)(n0 + rb) * K + g * 8;
  char* ldsA = smA + w * 4096;            // 32 rows * 128B
  char* ldsB = smB + w * 4096;

  f32x4 acc[4][4] = {};
  for (int k0 = 0; k0 < K; k0 += BKT) {
    __syncthreads();                       // previous compute done
#pragma unroll
    for (int i = 0; i < 4; ++i) {
      GLD16(pA + (size_t)i * 8 * K + k0, ldsA + i * 1024);
      GLD16(pB + (size_t)i * 8 * K + k0, ldsB + i * 1024);
    }
    __syncthreads();                       // compiler drains vmcnt before barrier
#pragma unroll
    for (int kk = 0; kk < BKT / 32; ++kk) {
      bf16x8 af[4], bb[4];
      int lk = kk * 4 + (l >> 4);
#pragma unroll
      for (int f = 0; f < 4; ++f) {
        int ar = wr * 64 + f * 16 + (l & 15);
        af[f] = *(const bf16x8*)(smA + ar * 128 + ((lk ^ (ar & 7)) << 4));
        int br = wc * 64 + f * 16 + (l & 15);
        bb[f] = *(const bf16x8*)(smB + br * 128 + ((lk ^ (br & 7)) << 4));
      }
#pragma unroll
      for (int i2 = 0; i2 < 4; ++i2)
#pragma unroll
        for (int j2 = 0; j2 < 4; ++j2)
          acc[i2][j2] = __builtin_amdgcn_mfma_f32_16x16x32_bf16(
              af[i2], bb[j2], acc[i2][j2], 0, 0, 0);
    }
  }
#pragma unroll
  for (int i2 = 0; i2 < 4; ++i2)
#pragma unroll
    for (int j2 = 0; j2 < 4; ++j2) {
      int col = n0 + wc * 64 + j2 * 16 + (l & 15);
      float cs = ws[col];
#pragma unroll
      for (int r = 0; r < 4; ++r) {
        int row = m0 + wr * 64 + i2 * 16 + (l >> 4) * 4 + r;
        Y[(size_t)row * N + col] = acc[i2][j2][r] * xs[row] * cs;
      }
    }
}

__global__ __launch_bounds__(256) void gemm2_kernel(
    const unsigned short* __restrict__ A,   // y1q: M x K
    const unsigned short* __restrict__ B,   // uq:  N x K
    const float* __restrict__ s2h, const float* __restrict__ s2l,
    const float* __restrict__ ush, const float* __restrict__ usl,
    const float* __restrict__ bias,
    float* __restrict__ Out, int M, int N, int K, int r_high) {
  __shared__ char smA[BM * BKT * 2];
  __shared__ char smB[BN * BKT * 2];
  int m0 = blockIdx.y * BM, n0 = blockIdx.x * BN;
  int tid = threadIdx.x, l = tid & 63, w = tid >> 6;
  int wr = w >> 1, wc = w & 1;

  int s8 = l & 7;
  int rb = w * 32 + (l >> 3);
  int g  = s8 ^ (rb & 7);
  const unsigned short* pA = A + (size_t)(m0 + rb) * K + g * 8;
  const unsigned short* pB = B + (size_t)(n0 + rb) * K + g * 8;
  char* ldsA = smA + w * 4096;
  char* ldsB = smB + w * 4096;

  f32x4 acch[4][4] = {};
  f32x4 accl[4][4] = {};

  auto ktile = [&](int k0, f32x4(&acc)[4][4]) {
    __syncthreads();
#pragma unroll
    for (int i = 0; i < 4; ++i) {
      GLD16(pA + (size_t)i * 8 * K + k0, ldsA + i * 1024);
      GLD16(pB + (size_t)i * 8 * K + k0, ldsB + i * 1024);
    }
    __syncthreads();
#pragma unroll
    for (int kk = 0; kk < BKT / 32; ++kk) {
      bf16x8 af[4], bb[4];
      int lk = kk * 4 + (l >> 4);
#pragma unroll
      for (int f = 0; f < 4; ++f) {
        int ar = wr * 64 + f * 16 + (l & 15);
        af[f] = *(const bf16x8*)(smA + ar * 128 + ((lk ^ (ar & 7)) << 4));
        int br = wc * 64 + f * 16 + (l & 15);
        bb[f] = *(const bf16x8*)(smB + br * 128 + ((lk ^ (br & 7)) << 4));
      }
#pragma unroll
      for (int i2 = 0; i2 < 4; ++i2)
#pragma unroll
        for (int j2 = 0; j2 < 4; ++j2)
          acc[i2][j2] = __builtin_amdgcn_mfma_f32_16x16x32_bf16(
              af[i2], bb[j2], acc[i2][j2], 0, 0, 0);
    }
  };

  for (int k0 = 0; k0 < r_high; k0 += BKT) ktile(k0, acch);   // high: k in [0,256)
  for (int k0 = r_high; k0 < K; k0 += BKT) ktile(k0, accl);   // low:  k in [256,1024)

#pragma unroll
  for (int i2 = 0; i2 < 4; ++i2)
#pragma unroll
    for (int j2 = 0; j2 < 4; ++j2) {
      int col = n0 + wc * 64 + j2 * 16 + (l & 15);
      float uh = ush[col], ul = usl[col];
      float bc = f16round(bias[col]);
#pragma unroll
      for (int r = 0; r < 4; ++r) {
        int row = m0 + wr * 64 + i2 * 16 + (l >> 4) * 4 + r;
        Out[(size_t)row * N + col] =
            acch[i2][j2][r] * (s2h[row] * uh) +
            accl[i2][j2][r] * (s2l[row] * ul) + bc;
      }
    }
}

// ---------- launch ----------

extern "C" void kernel_launch(void* const* d_in, const int* in_sizes, int n_in,
                              void* d_out, int out_size, void* d_ws, size_t ws_size,
                              hipStream_t stream) {
  const float* x    = (const float*)d_in[0];
  const float* uw   = (const float*)d_in[1];
  const float* vw   = (const float*)d_in[2];
  const float* bias = (const float*)d_in[3];
  const int*   hi   = (const int*)d_in[4];
  const int*   lo   = (const int*)d_in[5];

  const int in_f = 4096, out_f = 4096;
  const int rank   = in_sizes[1] / out_f;     // 1024
  const int r_high = in_sizes[4];             // 256
  const int M      = in_sizes[0] / in_f;      // 8192

  char* p = (char*)d_ws;
  auto take = [&](size_t bytes) {
    char* r = p;
    p += (bytes + 255) & ~(size_t)255;
    return r;
  };
  unsigned short* xq  = (unsigned short*)take((size_t)M * in_f * 2);
  float*          xs  = (float*)take((size_t)M * 4);
  unsigned short* vq  = (unsigned short*)take((size_t)rank * in_f * 2);
  float*          vs  = (float*)take((size_t)rank * 4);
  unsigned short* uq  = (unsigned short*)take((size_t)out_f * rank * 2);
  float*          ush = (float*)take((size_t)out_f * 4);
  float*          usl = (float*)take((size_t)out_f * 4);
  float*          y1  = (float*)take((size_t)M * rank * 4);
  unsigned short* y1q = (unsigned short*)take((size_t)M * rank * 2);
  float*          s2h = (float*)take((size_t)M * 4);
  float*          s2l = (float*)take((size_t)M * 4);

  quant_x_kernel<<<M, 256, 0, stream>>>(x, xq, xs, in_f);
  quant_v_kernel<<<rank, 256, 0, stream>>>(vw, hi, lo, r_high, vq, vs, in_f);
  quant_u_kernel<<<out_f, 256, 0, stream>>>(uw, hi, lo, r_high, rank, uq, ush, usl);
  gemm1_kernel<<<dim3(rank / BN, M / BM), 256, 0, stream>>>(xq, vq, xs, vs, y1,
                                                            M, rank, in_f);
  quant_y1_kernel<<<M, 256, 0, stream>>>(y1, y1q, s2h, s2l, rank, r_high);
  gemm2_kernel<<<dim3(out_f / BN, M / BM), 256, 0, stream>>>(
      y1q, uq, s2h, s2l, ush, usl, bias, (float*)d_out, M, out_f, rank, r_high);
}

// Round 3
// 211.033 us; speedup vs baseline: 2.1772x; 1.4944x over previous
//
#include <hip/hip_runtime.h>
#include <hip/hip_bf16.h>
#include <hip/hip_fp16.h>

typedef int   i32x4 __attribute__((ext_vector_type(4)));
typedef float f32x4 __attribute__((ext_vector_type(4)));

// global -> LDS direct DMA, 16B per lane, linear LDS dest (base + lane*16)
#define GLD16(gp, lp)                                                   \
  __builtin_amdgcn_global_load_lds(                                     \
      (const __attribute__((address_space(1))) unsigned int*)(gp),      \
      (__attribute__((address_space(3))) unsigned int*)(lp), 16, 0, 0)

// ---------- helpers ----------

__device__ inline float blk_absmax(float v, float* red) {
#pragma unroll
  for (int off = 32; off; off >>= 1) v = fmaxf(v, __shfl_xor(v, off));
  __syncthreads();                       // protect red[] reuse across calls
  if ((threadIdx.x & 63) == 0) red[threadIdx.x >> 6] = v;
  __syncthreads();
  return fmaxf(fmaxf(red[0], red[1]), fmaxf(red[2], red[3]));
}

__device__ inline float f16round(float s) {   // s.astype(f16).astype(f32)
  return __half2float(__float2half(s));
}

__device__ inline float qclip(float x, float s, float qmax) {
  return fminf(fmaxf(rintf(x / s), -qmax), qmax);   // rintf = round-half-even (matches jnp.round)
}

// ---------- activation quant: x (M x 4096 f32) -> xq i8 + xs f32 ----------

__global__ __launch_bounds__(256) void quant_x_kernel(
    const float* __restrict__ x, char* __restrict__ xq,
    float* __restrict__ xs, int C) {
  __shared__ float red[4];
  int row = blockIdx.x, t = threadIdx.x;
  const float4* src = (const float4*)(x + (size_t)row * C);
  float4 v[4];
  float m = 0.f;
#pragma unroll
  for (int i = 0; i < 4; ++i) {
    v[i] = src[t + i * 256];
    m = fmaxf(m, fmaxf(fmaxf(fabsf(v[i].x), fabsf(v[i].y)),
                       fmaxf(fabsf(v[i].z), fabsf(v[i].w))));
  }
  m = blk_absmax(m, red);
  float s = fmaxf(m, 1e-8f) / 127.0f;     // x_scale stays fp32 (no f16 round)
  if (t == 0) xs[row] = s;
  char4* dst = (char4*)(xq + (size_t)row * C);
#pragma unroll
  for (int i = 0; i < 4; ++i) {
    char4 o;
    o.x = (char)qclip(v[i].x, s, 127.f);
    o.y = (char)qclip(v[i].y, s, 127.f);
    o.z = (char)qclip(v[i].z, s, 127.f);
    o.w = (char)qclip(v[i].w, s, 127.f);
    dst[t + i * 256] = o;
  }
}

// ---------- weight quant: v rows (gathered), high qmax=127, low qmax=7 ----------

__global__ __launch_bounds__(256) void quant_v_kernel(
    const float* __restrict__ vw, const int* __restrict__ hi,
    const int* __restrict__ lo, int r_high,
    char* __restrict__ vq, float* __restrict__ vs, int C) {
  __shared__ float red[4];
  int b = blockIdx.x, t = threadIdx.x;
  int srow; float qmax;
  if (b < r_high) { srow = hi[b]; qmax = 127.f; }
  else            { srow = lo[b - r_high]; qmax = 7.f; }
  const float4* src = (const float4*)(vw + (size_t)srow * C);
  float4 v[4];
  float m = 0.f;
#pragma unroll
  for (int i = 0; i < 4; ++i) {
    v[i] = src[t + i * 256];
    m = fmaxf(m, fmaxf(fmaxf(fabsf(v[i].x), fabsf(v[i].y)),
                       fmaxf(fabsf(v[i].z), fabsf(v[i].w))));
  }
  m = blk_absmax(m, red);
  float s = fmaxf(m, 1e-8f) / qmax;       // quantize with fp32 scale
  if (t == 0) vs[b] = f16round(s);        // but output-scale goes through f16
  char4* dst = (char4*)(vq + (size_t)b * C);
#pragma unroll
  for (int i = 0; i < 4; ++i) {
    char4 o;
    o.x = (char)qclip(v[i].x, s, qmax);
    o.y = (char)qclip(v[i].y, s, qmax);
    o.z = (char)qclip(v[i].z, s, qmax);
    o.w = (char)qclip(v[i].w, s, qmax);
    dst[t + i * 256] = o;
  }
}

// ---------- weight quant: u rows = u_weight[i, idx] gathered columns ----------
// uq combined layout: row i = [high cols 0..255 | low cols 256..1023]

__global__ __launch_bounds__(256) void quant_u_kernel(
    const float* __restrict__ uw, const int* __restrict__ hi,
    const int* __restrict__ lo, int r_high, int rank,
    char* __restrict__ uq, float* __restrict__ ush,
    float* __restrict__ usl) {
  __shared__ float red[4];
  int i = blockIdx.x, t = threadIdx.x;
  const float* urow = uw + (size_t)i * rank;
  // high path (r_high == 256 == blockDim)
  float hv = urow[hi[t]];
  float mh = blk_absmax(fabsf(hv), red);
  float sh = fmaxf(mh, 1e-8f) / 127.f;
  uq[(size_t)i * rank + t] = (char)qclip(hv, sh, 127.f);
  if (t == 0) ush[i] = f16round(sh);
  // low path (768 = 3*256)
  float lv[3]; float ml = 0.f;
#pragma unroll
  for (int j = 0; j < 3; ++j) {
    lv[j] = urow[lo[t + j * 256]];
    ml = fmaxf(ml, fabsf(lv[j]));
  }
  ml = blk_absmax(ml, red);
  float sl = fmaxf(ml, 1e-8f) / 7.f;
#pragma unroll
  for (int j = 0; j < 3; ++j)
    uq[(size_t)i * rank + r_high + t + j * 256] = (char)qclip(lv[j], sl, 7.f);
  if (t == 0) usl[i] = f16round(sl);
}

// ---------- re-quant of y1: split-row absmax (high cols [0,256), low [256,1024)) ----------

__global__ __launch_bounds__(256) void quant_y1_kernel(
    const float* __restrict__ y1, char* __restrict__ y1q,
    float* __restrict__ s2h, float* __restrict__ s2l, int N, int r_high) {
  __shared__ float red[4];
  int row = blockIdx.x, t = threadIdx.x;
  float4 v = ((const float4*)(y1 + (size_t)row * N))[t];
  float a = fmaxf(fmaxf(fabsf(v.x), fabsf(v.y)), fmaxf(fabsf(v.z), fabsf(v.w)));
  bool ishigh = (t * 4) < r_high;
  float mh = blk_absmax(ishigh ? a : 0.f, red);
  float ml = blk_absmax(ishigh ? 0.f : a, red);
  float sh = fmaxf(mh, 1e-8f) / 127.f;
  float sl = fmaxf(ml, 1e-8f) / 127.f;
  float s = ishigh ? sh : sl;
  char4 o;
  o.x = (char)qclip(v.x, s, 127.f);
  o.y = (char)qclip(v.y, s, 127.f);
  o.z = (char)qclip(v.z, s, 127.f);
  o.w = (char)qclip(v.w, s, 127.f);
  ((char4*)(y1q + (size_t)row * N))[t] = o;
  if (t == 0) { s2h[row] = sh; s2l[row] = sl; }
}

// ---------- GEMM common geometry (m97 structure, int8) ----------
// 128x128 tile, BK=128 i8 elements (= 128 BYTES per row, same byte geometry
// as the verified bf16 BK=64 tile). 256 threads = 4 waves in 2x2; each wave
// 64x64 out = 4x4 frags of mfma_i32_16x16x64_i8 (i32 exact accumulation).
// Staging: global_load_lds width=16, linear LDS dest; XOR swizzle
// ((byte_grp) ^ (row&7)) applied to the GLOBAL source address so swizzled
// ds_read_b128 reads are conflict-free (rule #21: same involution both sides).

#define BM 128
#define BN 128
#define BKT 128   // i8 elements per K-tile = bytes per LDS row

__global__ __launch_bounds__(256) void gemm1_kernel(
    const char* __restrict__ A,   // xq: M x K i8
    const char* __restrict__ B,   // vq: N x K i8
    const float* __restrict__ xs, const float* __restrict__ ws,
    float* __restrict__ Y, int M, int N, int K) {
  __shared__ char smA[BM * BKT];
  __shared__ char smB[BN * BKT];
  int m0 = blockIdx.y * BM, n0 = blockIdx.x * BN;
  int tid = threadIdx.x, l = tid & 63, w = tid >> 6;
  int wr = w >> 1, wc = w & 1;

  // staging geometry: wave w stages rows [w*32, w*32+32), 4 calls x 8 rows;
  // lane l -> row rb + i*8, 16B slot (l&7), source group pre-swizzled.
  int s8 = l & 7;
  int rb = w * 32 + (l >> 3);
  int g  = s8 ^ (rb & 7);
  const char* pA = A + (size_t)(m0 + rb) * K + g * 16;
  const char* pB = B + (size_t)(n0 + rb) * K + g * 16;
  char* ldsA = smA + w * 4096;            // 32 rows * 128B
  char* ldsB = smB + w * 4096;

  i32x4 acc[4][4] = {};
  for (int k0 = 0; k0 < K; k0 += BKT) {
    __syncthreads();                       // previous compute done
#pragma unroll
    for (int i = 0; i < 4; ++i) {
      GLD16(pA + (size_t)i * 8 * K + k0, ldsA + i * 1024);
      GLD16(pB + (size_t)i * 8 * K + k0, ldsB + i * 1024);
    }
    __syncthreads();                       // compiler drains vmcnt before barrier
#pragma unroll
    for (int kk = 0; kk < BKT / 64; ++kk) {
      i32x4 af[4], bb[4];
      int lk = kk * 4 + (l >> 4);          // 16B group within 128B row
#pragma unroll
      for (int f = 0; f < 4; ++f) {
        int ar = wr * 64 + f * 16 + (l & 15);
        af[f] = *(const i32x4*)(smA + ar * 128 + ((lk ^ (ar & 7)) << 4));
        int br = wc * 64 + f * 16 + (l & 15);
        bb[f] = *(const i32x4*)(smB + br * 128 + ((lk ^ (br & 7)) << 4));
      }
#pragma unroll
      for (int i2 = 0; i2 < 4; ++i2)
#pragma unroll
        for (int j2 = 0; j2 < 4; ++j2)
          acc[i2][j2] = __builtin_amdgcn_mfma_i32_16x16x64_i8(
              af[i2], bb[j2], acc[i2][j2], 0, 0, 0);
    }
  }
#pragma unroll
  for (int i2 = 0; i2 < 4; ++i2)
#pragma unroll
    for (int j2 = 0; j2 < 4; ++j2) {
      int col = n0 + wc * 64 + j2 * 16 + (l & 15);
      float cs = ws[col];
#pragma unroll
      for (int r = 0; r < 4; ++r) {
        int row = m0 + wr * 64 + i2 * 16 + (l >> 4) * 4 + r;
        Y[(size_t)row * N + col] = (float)acc[i2][j2][r] * xs[row] * cs;
      }
    }
}

__global__ __launch_bounds__(256) void gemm2_kernel(
    const char* __restrict__ A,   // y1q: M x K i8
    const char* __restrict__ B,   // uq:  N x K i8
    const float* __restrict__ s2h, const float* __restrict__ s2l,
    const float* __restrict__ ush, const float* __restrict__ usl,
    const float* __restrict__ bias,
    float* __restrict__ Out, int M, int N, int K, int r_high) {
  __shared__ char smA[BM * BKT];
  __shared__ char smB[BN * BKT];
  int m0 = blockIdx.y * BM, n0 = blockIdx.x * BN;
  int tid = threadIdx.x, l = tid & 63, w = tid >> 6;
  int wr = w >> 1, wc = w & 1;

  int s8 = l & 7;
  int rb = w * 32 + (l >> 3);
  int g  = s8 ^ (rb & 7);
  const char* pA = A + (size_t)(m0 + rb) * K + g * 16;
  const char* pB = B + (size_t)(n0 + rb) * K + g * 16;
  char* ldsA = smA + w * 4096;
  char* ldsB = smB + w * 4096;

  i32x4 acch[4][4] = {};
  i32x4 accl[4][4] = {};

  auto ktile = [&](int k0, i32x4(&acc)[4][4]) {
    __syncthreads();
#pragma unroll
    for (int i = 0; i < 4; ++i) {
      GLD16(pA + (size_t)i * 8 * K + k0, ldsA + i * 1024);
      GLD16(pB + (size_t)i * 8 * K + k0, ldsB + i * 1024);
    }
    __syncthreads();
#pragma unroll
    for (int kk = 0; kk < BKT / 64; ++kk) {
      i32x4 af[4], bb[4];
      int lk = kk * 4 + (l >> 4);
#pragma unroll
      for (int f = 0; f < 4; ++f) {
        int ar = wr * 64 + f * 16 + (l & 15);
        af[f] = *(const i32x4*)(smA + ar * 128 + ((lk ^ (ar & 7)) << 4));
        int br = wc * 64 + f * 16 + (l & 15);
        bb[f] = *(const i32x4*)(smB + br * 128 + ((lk ^ (br & 7)) << 4));
      }
#pragma unroll
      for (int i2 = 0; i2 < 4; ++i2)
#pragma unroll
        for (int j2 = 0; j2 < 4; ++j2)
          acc[i2][j2] = __builtin_amdgcn_mfma_i32_16x16x64_i8(
              af[i2], bb[j2], acc[i2][j2], 0, 0, 0);
    }
  };

  for (int k0 = 0; k0 < r_high; k0 += BKT) ktile(k0, acch);   // high: k in [0,256)
  for (int k0 = r_high; k0 < K; k0 += BKT) ktile(k0, accl);   // low:  k in [256,1024)

#pragma unroll
  for (int i2 = 0; i2 < 4; ++i2)
#pragma unroll
    for (int j2 = 0; j2 < 4; ++j2) {
      int col = n0 + wc * 64 + j2 * 16 + (l & 15);
      float uh = ush[col], ul = usl[col];
      float bc = f16round(bias[col]);
#pragma unroll
      for (int r = 0; r < 4; ++r) {
        int row = m0 + wr * 64 + i2 * 16 + (l >> 4) * 4 + r;
        Out[(size_t)row * N + col] =
            (float)acch[i2][j2][r] * (s2h[row] * uh) +
            (float)accl[i2][j2][r] * (s2l[row] * ul) + bc;
      }
    }
}

// ---------- launch ----------

extern "C" void kernel_launch(void* const* d_in, const int* in_sizes, int n_in,
                              void* d_out, int out_size, void* d_ws, size_t ws_size,
                              hipStream_t stream) {
  const float* x    = (const float*)d_in[0];
  const float* uw   = (const float*)d_in[1];
  const float* vw   = (const float*)d_in[2];
  const float* bias = (const float*)d_in[3];
  const int*   hi   = (const int*)d_in[4];
  const int*   lo   = (const int*)d_in[5];

  const int in_f = 4096, out_f = 4096;
  const int rank   = in_sizes[1] / out_f;     // 1024
  const int r_high = in_sizes[4];             // 256
  const int M      = in_sizes[0] / in_f;      // 8192

  char* p = (char*)d_ws;
  auto take = [&](size_t bytes) {
    char* r = p;
    p += (bytes + 255) & ~(size_t)255;
    return r;
  };
  char*  xq  = take((size_t)M * in_f);
  float* xs  = (float*)take((size_t)M * 4);
  char*  vq  = take((size_t)rank * in_f);
  float* vs  = (float*)take((size_t)rank * 4);
  char*  uq  = take((size_t)out_f * rank);
  float* ush = (float*)take((size_t)out_f * 4);
  float* usl = (float*)take((size_t)out_f * 4);
  float* y1  = (float*)take((size_t)M * rank * 4);
  char*  y1q = take((size_t)M * rank);
  float* s2h = (float*)take((size_t)M * 4);
  float* s2l = (float*)take((size_t)M * 4);

  quant_x_kernel<<<M, 256, 0, stream>>>(x, xq, xs, in_f);
  quant_v_kernel<<<rank, 256, 0, stream>>>(vw, hi, lo, r_high, vq, vs, in_f);
  quant_u_kernel<<<out_f, 256, 0, stream>>>(uw, hi, lo, r_high, rank, uq, ush, usl);
  gemm1_kernel<<<dim3(rank / BN, M / BM), 256, 0, stream>>>(xq, vq, xs, vs, y1,
                                                            M, rank, in_f);
  quant_y1_kernel<<<M, 256, 0, stream>>>(y1, y1q, s2h, s2l, rank, r_high);
  gemm2_kernel<<<dim3(out_f / BN, M / BM), 256, 0, stream>>>(
      y1q, uq, s2h, s2l, ush, usl, bias, (float*)d_out, M, out_f, rank, r_high);
}

// Round 4
// 170.898 us; speedup vs baseline: 2.6885x; 1.2348x over previous
//
#include <hip/hip_runtime.h>
#include <hip/hip_bf16.h>
#include <hip/hip_fp16.h>

typedef int   i32x4 __attribute__((ext_vector_type(4)));
typedef float f32x4 __attribute__((ext_vector_type(4)));

// global -> LDS direct DMA, 16B per lane, linear LDS dest (base + lane*16)
#define GLD16(gp, lp)                                                   \
  __builtin_amdgcn_global_load_lds(                                     \
      (const __attribute__((address_space(1))) unsigned int*)(gp),      \
      (__attribute__((address_space(3))) unsigned int*)(lp), 16, 0, 0)

// ---------- helpers ----------

__device__ inline float blk_absmax(float v, float* red) {
#pragma unroll
  for (int off = 32; off; off >>= 1) v = fmaxf(v, __shfl_xor(v, off));
  __syncthreads();                       // protect red[] reuse across calls
  if ((threadIdx.x & 63) == 0) red[threadIdx.x >> 6] = v;
  __syncthreads();
  return fmaxf(fmaxf(red[0], red[1]), fmaxf(red[2], red[3]));
}

__device__ inline float f16round(float s) {   // s.astype(f16).astype(f32)
  return __half2float(__float2half(s));
}

__device__ inline float qclip(float x, float s, float qmax) {
  return fminf(fmaxf(rintf(x / s), -qmax), qmax);   // rintf = round-half-even (matches jnp.round)
}

// ---------- activation quant: x (M x 4096 f32) -> xq i8 + xs f32 ----------

__global__ __launch_bounds__(256) void quant_x_kernel(
    const float* __restrict__ x, char* __restrict__ xq,
    float* __restrict__ xs, int C) {
  __shared__ float red[4];
  int row = blockIdx.x, t = threadIdx.x;
  const float4* src = (const float4*)(x + (size_t)row * C);
  float4 v[4];
  float m = 0.f;
#pragma unroll
  for (int i = 0; i < 4; ++i) {
    v[i] = src[t + i * 256];
    m = fmaxf(m, fmaxf(fmaxf(fabsf(v[i].x), fabsf(v[i].y)),
                       fmaxf(fabsf(v[i].z), fabsf(v[i].w))));
  }
  m = blk_absmax(m, red);
  float s = fmaxf(m, 1e-8f) / 127.0f;     // x_scale stays fp32 (no f16 round)
  if (t == 0) xs[row] = s;
  char4* dst = (char4*)(xq + (size_t)row * C);
#pragma unroll
  for (int i = 0; i < 4; ++i) {
    char4 o;
    o.x = (char)qclip(v[i].x, s, 127.f);
    o.y = (char)qclip(v[i].y, s, 127.f);
    o.z = (char)qclip(v[i].z, s, 127.f);
    o.w = (char)qclip(v[i].w, s, 127.f);
    dst[t + i * 256] = o;
  }
}

// ---------- weight quant: v rows (gathered), high qmax=127, low qmax=7 ----------

__global__ __launch_bounds__(256) void quant_v_kernel(
    const float* __restrict__ vw, const int* __restrict__ hi,
    const int* __restrict__ lo, int r_high,
    char* __restrict__ vq, float* __restrict__ vs, int C) {
  __shared__ float red[4];
  int b = blockIdx.x, t = threadIdx.x;
  int srow; float qmax;
  if (b < r_high) { srow = hi[b]; qmax = 127.f; }
  else            { srow = lo[b - r_high]; qmax = 7.f; }
  const float4* src = (const float4*)(vw + (size_t)srow * C);
  float4 v[4];
  float m = 0.f;
#pragma unroll
  for (int i = 0; i < 4; ++i) {
    v[i] = src[t + i * 256];
    m = fmaxf(m, fmaxf(fmaxf(fabsf(v[i].x), fabsf(v[i].y)),
                       fmaxf(fabsf(v[i].z), fabsf(v[i].w))));
  }
  m = blk_absmax(m, red);
  float s = fmaxf(m, 1e-8f) / qmax;       // quantize with fp32 scale
  if (t == 0) vs[b] = f16round(s);        // but output-scale goes through f16
  char4* dst = (char4*)(vq + (size_t)b * C);
#pragma unroll
  for (int i = 0; i < 4; ++i) {
    char4 o;
    o.x = (char)qclip(v[i].x, s, qmax);
    o.y = (char)qclip(v[i].y, s, qmax);
    o.z = (char)qclip(v[i].z, s, qmax);
    o.w = (char)qclip(v[i].w, s, qmax);
    dst[t + i * 256] = o;
  }
}

// ---------- weight quant: u rows = u_weight[i, idx] gathered columns ----------
// uq combined layout: row i = [high cols 0..255 | low cols 256..1023]

__global__ __launch_bounds__(256) void quant_u_kernel(
    const float* __restrict__ uw, const int* __restrict__ hi,
    const int* __restrict__ lo, int r_high, int rank,
    char* __restrict__ uq, float* __restrict__ ush,
    float* __restrict__ usl) {
  __shared__ float red[4];
  int i = blockIdx.x, t = threadIdx.x;
  const float* urow = uw + (size_t)i * rank;
  // high path (r_high == 256 == blockDim)
  float hv = urow[hi[t]];
  float mh = blk_absmax(fabsf(hv), red);
  float sh = fmaxf(mh, 1e-8f) / 127.f;
  uq[(size_t)i * rank + t] = (char)qclip(hv, sh, 127.f);
  if (t == 0) ush[i] = f16round(sh);
  // low path (768 = 3*256)
  float lv[3]; float ml = 0.f;
#pragma unroll
  for (int j = 0; j < 3; ++j) {
    lv[j] = urow[lo[t + j * 256]];
    ml = fmaxf(ml, fabsf(lv[j]));
  }
  ml = blk_absmax(ml, red);
  float sl = fmaxf(ml, 1e-8f) / 7.f;
#pragma unroll
  for (int j = 0; j < 3; ++j)
    uq[(size_t)i * rank + r_high + t + j * 256] = (char)qclip(lv[j], sl, 7.f);
  if (t == 0) usl[i] = f16round(sl);
}

// ---------- re-quant of y1: split-row absmax (high cols [0,256), low [256,1024)) ----------

__global__ __launch_bounds__(256) void quant_y1_kernel(
    const float* __restrict__ y1, char* __restrict__ y1q,
    float* __restrict__ s2h, float* __restrict__ s2l, int N, int r_high) {
  __shared__ float red[4];
  int row = blockIdx.x, t = threadIdx.x;
  float4 v = ((const float4*)(y1 + (size_t)row * N))[t];
  float a = fmaxf(fmaxf(fabsf(v.x), fabsf(v.y)), fmaxf(fabsf(v.z), fabsf(v.w)));
  bool ishigh = (t * 4) < r_high;
  float mh = blk_absmax(ishigh ? a : 0.f, red);
  float ml = blk_absmax(ishigh ? 0.f : a, red);
  float sh = fmaxf(mh, 1e-8f) / 127.f;
  float sl = fmaxf(ml, 1e-8f) / 127.f;
  float s = ishigh ? sh : sl;
  char4 o;
  o.x = (char)qclip(v.x, s, 127.f);
  o.y = (char)qclip(v.y, s, 127.f);
  o.z = (char)qclip(v.z, s, 127.f);
  o.w = (char)qclip(v.w, s, 127.f);
  ((char4*)(y1q + (size_t)row * N))[t] = o;
  if (t == 0) { s2h[row] = sh; s2l[row] = sl; }
}

// ---------- GEMM geometry (occupancy-fixed int8, m97-style staging) ----------
// Block tile 64(M) x 128(N), BK = 128 i8 elements (128 BYTES per LDS row).
// 256 threads = 4 waves in 2x2; wave tile 32x64 = 2x4 frags of
// mfma_i32_16x16x64_i8.  Dual-acc (gemm2) = 64 regs, single (gemm1) = 32.
// Staging: global_load_lds width=16, linear LDS dest; XOR swizzle
// g = (l&7) ^ (row&7) pre-applied to the GLOBAL source address so swizzled
// ds_read_b128 reads are conflict-free (rule #21; row&7 invariant across
// 32-row staging rounds).  LDS 24 KB/block.

#define BM 64
#define BN 128
#define BKT 128   // i8 elements per K-tile = bytes per LDS row

__global__ __launch_bounds__(256, 4) void gemm1_kernel(
    const char* __restrict__ A,   // xq: M x K i8
    const char* __restrict__ B,   // vq: N x K i8
    const float* __restrict__ xs, const float* __restrict__ ws,
    float* __restrict__ Y, int M, int N, int K) {
  __shared__ char smA[BM * BKT];   // 8 KB
  __shared__ char smB[BN * BKT];   // 16 KB
  int m0 = blockIdx.y * BM, n0 = blockIdx.x * BN;
  int tid = threadIdx.x, l = tid & 63, w = tid >> 6;
  int wr = w >> 1, wc = w & 1;

  // staging: round i covers rows [i*32, i*32+32); lane -> row rb, slot l&7
  int rb = w * 8 + (l >> 3);                // 0..31
  int g  = (l & 7) ^ (rb & 7);              // pre-swizzled 16B group
  const char* pA = A + (size_t)(m0 + rb) * K + g * 16;
  const char* pB = B + (size_t)(n0 + rb) * K + g * 16;
  char* ldsA = smA + w * 1024;              // + l*16 linear per wave
  char* ldsB = smB + w * 1024;

  i32x4 acc[2][4] = {};
  for (int k0 = 0; k0 < K; k0 += BKT) {
    __syncthreads();
#pragma unroll
    for (int i = 0; i < 2; ++i)
      GLD16(pA + (size_t)i * 32 * K + k0, ldsA + i * 4096);
#pragma unroll
    for (int i = 0; i < 4; ++i)
      GLD16(pB + (size_t)i * 32 * K + k0, ldsB + i * 4096);
    __syncthreads();
#pragma unroll
    for (int kk = 0; kk < 2; ++kk) {
      i32x4 af[2], bb[4];
      int lk = kk * 4 + (l >> 4);
#pragma unroll
      for (int f = 0; f < 2; ++f) {
        int ar = wr * 32 + f * 16 + (l & 15);
        af[f] = *(const i32x4*)(smA + ar * 128 + ((lk ^ (ar & 7)) << 4));
      }
#pragma unroll
      for (int f = 0; f < 4; ++f) {
        int br = wc * 64 + f * 16 + (l & 15);
        bb[f] = *(const i32x4*)(smB + br * 128 + ((lk ^ (br & 7)) << 4));
      }
#pragma unroll
      for (int i2 = 0; i2 < 2; ++i2)
#pragma unroll
        for (int j2 = 0; j2 < 4; ++j2)
          acc[i2][j2] = __builtin_amdgcn_mfma_i32_16x16x64_i8(
              af[i2], bb[j2], acc[i2][j2], 0, 0, 0);
    }
  }
#pragma unroll
  for (int i2 = 0; i2 < 2; ++i2)
#pragma unroll
    for (int j2 = 0; j2 < 4; ++j2) {
      int col = n0 + wc * 64 + j2 * 16 + (l & 15);
      float cs = ws[col];
#pragma unroll
      for (int r = 0; r < 4; ++r) {
        int row = m0 + wr * 32 + i2 * 16 + (l >> 4) * 4 + r;
        Y[(size_t)row * N + col] = (float)acc[i2][j2][r] * xs[row] * cs;
      }
    }
}

__global__ __launch_bounds__(256, 3) void gemm2_kernel(
    const char* __restrict__ A,   // y1q: M x K i8
    const char* __restrict__ B,   // uq:  N x K i8
    const float* __restrict__ s2h, const float* __restrict__ s2l,
    const float* __restrict__ ush, const float* __restrict__ usl,
    const float* __restrict__ bias,
    float* __restrict__ Out, int M, int N, int K, int r_high) {
  __shared__ char smA[BM * BKT];
  __shared__ char smB[BN * BKT];
  int m0 = blockIdx.y * BM, n0 = blockIdx.x * BN;
  int tid = threadIdx.x, l = tid & 63, w = tid >> 6;
  int wr = w >> 1, wc = w & 1;

  int rb = w * 8 + (l >> 3);
  int g  = (l & 7) ^ (rb & 7);
  const char* pA = A + (size_t)(m0 + rb) * K + g * 16;
  const char* pB = B + (size_t)(n0 + rb) * K + g * 16;
  char* ldsA = smA + w * 1024;
  char* ldsB = smB + w * 1024;

  i32x4 acch[2][4] = {};
  i32x4 accl[2][4] = {};

  auto ktile = [&](int k0, i32x4(&acc)[2][4]) {
    __syncthreads();
#pragma unroll
    for (int i = 0; i < 2; ++i)
      GLD16(pA + (size_t)i * 32 * K + k0, ldsA + i * 4096);
#pragma unroll
    for (int i = 0; i < 4; ++i)
      GLD16(pB + (size_t)i * 32 * K + k0, ldsB + i * 4096);
    __syncthreads();
#pragma unroll
    for (int kk = 0; kk < 2; ++kk) {
      i32x4 af[2], bb[4];
      int lk = kk * 4 + (l >> 4);
#pragma unroll
      for (int f = 0; f < 2; ++f) {
        int ar = wr * 32 + f * 16 + (l & 15);
        af[f] = *(const i32x4*)(smA + ar * 128 + ((lk ^ (ar & 7)) << 4));
      }
#pragma unroll
      for (int f = 0; f < 4; ++f) {
        int br = wc * 64 + f * 16 + (l & 15);
        bb[f] = *(const i32x4*)(smB + br * 128 + ((lk ^ (br & 7)) << 4));
      }
#pragma unroll
      for (int i2 = 0; i2 < 2; ++i2)
#pragma unroll
        for (int j2 = 0; j2 < 4; ++j2)
          acc[i2][j2] = __builtin_amdgcn_mfma_i32_16x16x64_i8(
              af[i2], bb[j2], acc[i2][j2], 0, 0, 0);
    }
  };

  for (int k0 = 0; k0 < r_high; k0 += BKT) ktile(k0, acch);   // high: k in [0,256)
  for (int k0 = r_high; k0 < K; k0 += BKT) ktile(k0, accl);   // low:  k in [256,1024)

#pragma unroll
  for (int i2 = 0; i2 < 2; ++i2)
#pragma unroll
    for (int j2 = 0; j2 < 4; ++j2) {
      int col = n0 + wc * 64 + j2 * 16 + (l & 15);
      float uh = ush[col], ul = usl[col];
      float bc = f16round(bias[col]);
#pragma unroll
      for (int r = 0; r < 4; ++r) {
        int row = m0 + wr * 32 + i2 * 16 + (l >> 4) * 4 + r;
        Out[(size_t)row * N + col] =
            (float)acch[i2][j2][r] * (s2h[row] * uh) +
            (float)accl[i2][j2][r] * (s2l[row] * ul) + bc;
      }
    }
}

// ---------- launch ----------

extern "C" void kernel_launch(void* const* d_in, const int* in_sizes, int n_in,
                              void* d_out, int out_size, void* d_ws, size_t ws_size,
                              hipStream_t stream) {
  const float* x    = (const float*)d_in[0];
  const float* uw   = (const float*)d_in[1];
  const float* vw   = (const float*)d_in[2];
  const float* bias = (const float*)d_in[3];
  const int*   hi   = (const int*)d_in[4];
  const int*   lo   = (const int*)d_in[5];

  const int in_f = 4096, out_f = 4096;
  const int rank   = in_sizes[1] / out_f;     // 1024
  const int r_high = in_sizes[4];             // 256
  const int M      = in_sizes[0] / in_f;      // 8192

  char* p = (char*)d_ws;
  auto take = [&](size_t bytes) {
    char* r = p;
    p += (bytes + 255) & ~(size_t)255;
    return r;
  };
  char*  xq  = take((size_t)M * in_f);
  float* xs  = (float*)take((size_t)M * 4);
  char*  vq  = take((size_t)rank * in_f);
  float* vs  = (float*)take((size_t)rank * 4);
  char*  uq  = take((size_t)out_f * rank);
  float* ush = (float*)take((size_t)out_f * 4);
  float* usl = (float*)take((size_t)out_f * 4);
  float* y1  = (float*)take((size_t)M * rank * 4);
  char*  y1q = take((size_t)M * rank);
  float* s2h = (float*)take((size_t)M * 4);
  float* s2l = (float*)take((size_t)M * 4);

  quant_x_kernel<<<M, 256, 0, stream>>>(x, xq, xs, in_f);
  quant_v_kernel<<<rank, 256, 0, stream>>>(vw, hi, lo, r_high, vq, vs, in_f);
  quant_u_kernel<<<out_f, 256, 0, stream>>>(uw, hi, lo, r_high, rank, uq, ush, usl);
  gemm1_kernel<<<dim3(rank / BN, M / BM), 256, 0, stream>>>(xq, vq, xs, vs, y1,
                                                            M, rank, in_f);
  quant_y1_kernel<<<M, 256, 0, stream>>>(y1, y1q, s2h, s2l, rank, r_high);
  gemm2_kernel<<<dim3(out_f / BN, M / BM), 256, 0, stream>>>(
      y1q, uq, s2h, s2l, ush, usl, bias, (float*)d_out, M, out_f, rank, r_high);
}